// Round 1
// baseline (1184.662 us; speedup 1.0000x reference)
//
#include <hip/hip_runtime.h>

// Problem constants (fixed by the reference).
#define D      256        // vq_embed_dim == C
#define N_E    16384      // codebook size
#define NPTS   8192       // B*H*W = 8*32*32
#define ZOUT   2097152    // 8*256*32*32 elements of z_hat_out
#define SPLIT  8          // code-dim split for the argmin GEMM
#define BM     64         // points per block
#define BN     128        // codes per chunk
#define BK     16         // k-slice per LDS B tile
#define CPS    (N_E / SPLIT)   // codes per split = 2048
#define CHUNKS (CPS / BN)      // 16
#define BIGF   3.0e38f

// ---------------------------------------------------------------------------
// Kernel 1: e2[j] = |emb_j|^2   (16384 rows x 256)
// ---------------------------------------------------------------------------
__global__ __launch_bounds__(64) void e2_kernel(const float* __restrict__ emb,
                                                float* __restrict__ e2) {
    const int row = blockIdx.x;
    const int t = threadIdx.x;  // 0..63, one wave
    const float4 v = *(const float4*)(emb + (size_t)row * D + t * 4);
    float s = v.x * v.x + v.y * v.y + v.z * v.z + v.w * v.w;
    #pragma unroll
    for (int off = 32; off > 0; off >>= 1) s += __shfl_down(s, off);
    if (t == 0) e2[row] = s;
}

// ---------------------------------------------------------------------------
// Kernel 2: fused fp32 GEMM + running argmin.
// Block: 64 points x 2048 codes (one of 8 code splits).
// A (64 pts x 256 k) lives in LDS for the whole block; B streamed 128x16.
// d(n,j) = e2[j] - 2 * <r_n, e_j>   (|r|^2 dropped: constant in j)
// ---------------------------------------------------------------------------
__global__ __launch_bounds__(256, 2) void argmin_gemm(
    const float* __restrict__ z, const float* __restrict__ emb,
    const float* __restrict__ e2,
    float* __restrict__ pmin, int* __restrict__ pidx) {
    __shared__ float As[D * BM];      // [k][p], 64 KB
    __shared__ float Bs[BK * 132];    // [k][j], padded 128->132 (bank + align)
    __shared__ float e2s[BN];

    const int tid = threadIdx.x;
    const int n0 = blockIdx.x * BM;       // first point of tile
    const int bb = n0 >> 10;              // batch (1024 points per batch)
    const int hw0 = n0 & 1023;
    const int split = blockIdx.y;
    const float* zb = z + (size_t)bb * (D * 1024) + hw0;

    // Load A tile once: residual[n0+p][k] = z[bb, k, hw0+p] (coalesced in p).
    {
        const int p4 = (tid & 15) * 4;
        const int k0 = tid >> 4;  // 0..15
        #pragma unroll
        for (int kk = 0; kk < 16; ++kk) {
            const int k = kk * 16 + k0;
            const float4 v = *(const float4*)(zb + k * 1024 + p4);
            *(float4*)(As + k * BM + p4) = v;
        }
    }

    const int cr = tid & 15;   // code group: 8 codes (2 x float4)
    const int pr = tid >> 4;   // point group: 4 points

    float best[4] = {BIGF, BIGF, BIGF, BIGF};
    int bidx[4] = {0, 0, 0, 0};

    for (int ch = 0; ch < CHUNKS; ++ch) {
        const int jbase = split * CPS + ch * BN;
        float acc[4][8] = {{0.0f}};

        __syncthreads();  // e2s (and A on first iter) safe to (re)write/use
        if (tid < BN) e2s[tid] = e2[jbase + tid];

        for (int kc = 0; kc < D / BK; ++kc) {
            // Load B tile: 128 codes x 16 k, row-major global -> [k][j] LDS.
            {
                const int k4 = tid & 3;   // which float4 in the 16-k slice
                const int jl = tid >> 2;  // 0..63
                #pragma unroll
                for (int jj = 0; jj < 2; ++jj) {
                    const int r = jj * 64 + jl;
                    const float4 v = *(const float4*)(
                        emb + (size_t)(jbase + r) * D + kc * BK + k4 * 4);
                    Bs[(k4 * 4 + 0) * 132 + r] = v.x;
                    Bs[(k4 * 4 + 1) * 132 + r] = v.y;
                    Bs[(k4 * 4 + 2) * 132 + r] = v.z;
                    Bs[(k4 * 4 + 3) * 132 + r] = v.w;
                }
            }
            __syncthreads();
            #pragma unroll
            for (int k = 0; k < BK; ++k) {
                const float4 a = *(const float4*)(As + (kc * BK + k) * BM + pr * 4);
                const float4 b0 = *(const float4*)(Bs + k * 132 + cr * 4);
                const float4 b1 = *(const float4*)(Bs + k * 132 + 64 + cr * 4);
                const float av[4] = {a.x, a.y, a.z, a.w};
                const float bv[8] = {b0.x, b0.y, b0.z, b0.w,
                                     b1.x, b1.y, b1.z, b1.w};
                #pragma unroll
                for (int p = 0; p < 4; ++p)
                    #pragma unroll
                    for (int j = 0; j < 8; ++j)
                        acc[p][j] += av[p] * bv[j];
            }
            __syncthreads();
        }

        // Fold this chunk into the running argmin (tie -> lowest index,
        // matching np.argmin first-occurrence).
        #pragma unroll
        for (int p = 0; p < 4; ++p) {
            #pragma unroll
            for (int g = 0; g < 2; ++g) {
                #pragma unroll
                for (int i = 0; i < 4; ++i) {
                    const int jl = g * 64 + cr * 4 + i;
                    const float dd = e2s[jl] - 2.0f * acc[p][g * 4 + i];
                    const int jg = jbase + jl;
                    if (dd < best[p] || (dd == best[p] && jg < bidx[p])) {
                        best[p] = dd;
                        bidx[p] = jg;
                    }
                }
            }
        }
    }

    // Cross-thread (over the 16 code groups) reduction via LDS (reuse As).
    __syncthreads();
    float* rmin = As;                       // [64][17]
    int* ridx = (int*)(As + 64 * 17);       // [64][17]
    #pragma unroll
    for (int p = 0; p < 4; ++p) {
        rmin[(pr * 4 + p) * 17 + cr] = best[p];
        ridx[(pr * 4 + p) * 17 + cr] = bidx[p];
    }
    __syncthreads();
    if (tid < 64) {
        float bm = BIGF;
        int bi = 0x7FFFFFFF;
        #pragma unroll
        for (int c = 0; c < 16; ++c) {
            const float v = rmin[tid * 17 + c];
            const int id = ridx[tid * 17 + c];
            if (v < bm || (v == bm && id < bi)) { bm = v; bi = id; }
        }
        pmin[(size_t)(n0 + tid) * SPLIT + split] = bm;
        pidx[(size_t)(n0 + tid) * SPLIT + split] = bi;
    }
}

// ---------------------------------------------------------------------------
// Kernel 3: reduce the 8 split-partials per point; emit final idx (int for the
// gather kernel) and total_idx (4 stacked copies, as float, into d_out).
// ---------------------------------------------------------------------------
__global__ __launch_bounds__(256) void finalize_argmin(
    const float* __restrict__ pmin, const int* __restrict__ pidx,
    int* __restrict__ idxf, float* __restrict__ out_idx) {
    const int n = blockIdx.x * 256 + threadIdx.x;  // 0..8191
    float bm = BIGF;
    int bi = 0x7FFFFFFF;
    #pragma unroll
    for (int s = 0; s < SPLIT; ++s) {
        const float v = pmin[(size_t)n * SPLIT + s];
        const int id = pidx[(size_t)n * SPLIT + s];
        if (v < bm || (v == bm && id < bi)) { bm = v; bi = id; }
    }
    idxf[n] = bi;
    const int b = n >> 10;
    const int hw = n & 1023;
    const float fv = (float)bi;
    #pragma unroll
    for (int s = 0; s < 4; ++s) out_idx[b * 4096 + s * 1024 + hw] = fv;
}

// ---------------------------------------------------------------------------
// Kernel 4: gather q = emb[idx], write z_hat_out = z + (4q - z), accumulate
// loss = 0.3125 * sum(30 q^2 - 20 q z + 4 z^2) / 2097152.
// Grid: (hw tiles of 32, c tiles of 8, b). Block 256 = 32 hw x 8 c.
// ---------------------------------------------------------------------------
__global__ __launch_bounds__(256) void quant_loss(
    const float* __restrict__ z, const float* __restrict__ emb,
    const int* __restrict__ idxf, float* __restrict__ out,
    float* __restrict__ loss) {
    __shared__ int idx_l[32];
    __shared__ float wsum[4];
    const int b = blockIdx.z;
    const int c0 = blockIdx.y * 8;
    const int hw0 = blockIdx.x * 32;
    const int t = threadIdx.x;
    const int hw_l = t & 31;
    const int c_l = t >> 5;
    if (t < 32) idx_l[t] = idxf[b * 1024 + hw0 + t];
    __syncthreads();
    const int j = idx_l[hw_l];
    const float q = emb[(size_t)j * D + c0 + c_l];
    const size_t zi = (size_t)b * 262144 + (size_t)(c0 + c_l) * 1024 + hw0 + hw_l;
    const float zv = z[zi];
    const float zh = ((q + q) + q) + q;   // mimic the 4-step accumulation
    out[zi] = zv + (zh - zv);
    float e = 30.0f * q * q - 20.0f * q * zv + 4.0f * zv * zv;
    #pragma unroll
    for (int off = 32; off > 0; off >>= 1) e += __shfl_down(e, off);
    if ((t & 63) == 0) wsum[t >> 6] = e;
    __syncthreads();
    if (t == 0) {
        const float s = wsum[0] + wsum[1] + wsum[2] + wsum[3];
        atomicAdd(loss, s * (0.3125f / 2097152.0f));
    }
}

// ---------------------------------------------------------------------------
extern "C" void kernel_launch(void* const* d_in, const int* in_sizes, int n_in,
                              void* d_out, int out_size, void* d_ws, size_t ws_size,
                              hipStream_t stream) {
    const float* z = (const float*)d_in[0];     // [8,256,32,32]
    const float* emb = (const float*)d_in[1];   // [16384,256]
    float* out = (float*)d_out;                 // z_hat_out | loss | total_idx

    // Workspace layout (~608 KB)
    float* e2 = (float*)d_ws;                   // 16384 f
    float* pmin = e2 + N_E;                     // 8192*8 f
    int* pidx = (int*)(pmin + NPTS * SPLIT);    // 8192*8 i
    int* idxf = pidx + NPTS * SPLIT;            // 8192 i

    float* loss = out + ZOUT;
    float* out_idx = out + ZOUT + 1;

    hipMemsetAsync(loss, 0, sizeof(float), stream);  // d_out is poisoned 0xAA
    e2_kernel<<<N_E, 64, 0, stream>>>(emb, e2);
    argmin_gemm<<<dim3(NPTS / BM, SPLIT), 256, 0, stream>>>(z, emb, e2, pmin, pidx);
    finalize_argmin<<<NPTS / 256, 256, 0, stream>>>(pmin, pidx, idxf, out_idx);
    quant_loss<<<dim3(32, 32, 8), 256, 0, stream>>>(z, emb, idxf, out, loss);
}

// Round 2
// 617.437 us; speedup vs baseline: 1.9187x; 1.9187x over previous
//
#include <hip/hip_runtime.h>

// Problem constants (fixed by the reference).
#define D      256        // vq_embed_dim == C
#define N_E    16384      // codebook size
#define NPTS   8192       // B*H*W
#define ZOUT   2097152    // elements of z_hat_out
#define KP     512        // packed K per matrix: [hi | lo]
#define BIGF   3.0e38f

typedef short bf16x8 __attribute__((ext_vector_type(8)));
typedef float f32x4 __attribute__((ext_vector_type(4)));
typedef unsigned long long u64;

__device__ __forceinline__ unsigned short f2bf(float x) {  // RNE
    unsigned int u = __float_as_uint(x);
    return (unsigned short)((u + 0x7FFFu + ((u >> 16) & 1u)) >> 16);
}
__device__ __forceinline__ float bf2f(unsigned short b) {
    return __uint_as_float(((unsigned int)b) << 16);
}
__device__ __forceinline__ void gl_lds16(const void* g, void* l) {
    __builtin_amdgcn_global_load_lds(
        (const __attribute__((address_space(1))) unsigned int*)g,
        (__attribute__((address_space(3))) unsigned int*)l, 16, 0, 0);
}

// ---------------------------------------------------------------------------
// Prep A: z[b,k,hw] -> Ap[n][0:256]=bf16hi, Ap[n][256:512]=bf16lo  (n=b*1024+hw)
// ---------------------------------------------------------------------------
__global__ __launch_bounds__(256) void prep_a(const float* __restrict__ z,
                                              unsigned short* __restrict__ Ap) {
    const int t = threadIdx.x;
    const int lane = t & 63, kg = t >> 6;
    const int n0 = blockIdx.x * 64;
    const int b = n0 >> 10, hw0 = n0 & 1023;
    const float* zb = z + (size_t)b * 262144 + hw0 + lane;
    unsigned short* orow = Ap + (size_t)(n0 + lane) * KP;
    for (int i = 0; i < 16; ++i) {
        const int k0 = i * 16 + kg * 4;
        ushort4 hv, lv;
        unsigned short* hp = (unsigned short*)&hv;
        unsigned short* lp = (unsigned short*)&lv;
        #pragma unroll
        for (int j = 0; j < 4; ++j) {
            const float v = zb[(size_t)(k0 + j) * 1024];   // coalesced per j
            const unsigned short hb = f2bf(v);
            hp[j] = hb;
            lp[j] = f2bf(v - bf2f(hb));
        }
        *(ushort4*)(orow + k0) = hv;
        *(ushort4*)(orow + 256 + k0) = lv;
    }
}

// ---------------------------------------------------------------------------
// Prep B: emb -> Bp[j][0:256]=hi, [256:512]=lo; also e2[j] = |emb_j|^2
// ---------------------------------------------------------------------------
__global__ __launch_bounds__(256) void prep_b(const float* __restrict__ emb,
                                              unsigned short* __restrict__ Bp,
                                              float* __restrict__ e2) {
    const int t = threadIdx.x;
    const int j = blockIdx.x * 64 + (t >> 2);
    const int q = t & 3;
    const float* row = emb + (size_t)j * 256 + q * 64;
    unsigned short* oh = Bp + (size_t)j * KP + q * 64;
    float s = 0.f;
    for (int i = 0; i < 16; ++i) {
        const float4 v = *(const float4*)(row + i * 4);
        s += v.x * v.x + v.y * v.y + v.z * v.z + v.w * v.w;
        const float vv[4] = {v.x, v.y, v.z, v.w};
        ushort4 hv, lv;
        unsigned short* hp = (unsigned short*)&hv;
        unsigned short* lp = (unsigned short*)&lv;
        #pragma unroll
        for (int c = 0; c < 4; ++c) {
            const unsigned short hb = f2bf(vv[c]);
            hp[c] = hb;
            lp[c] = f2bf(vv[c] - bf2f(hb));
        }
        *(ushort4*)(oh + i * 4) = hv;
        *(ushort4*)(oh + 256 + i * 4) = lv;
    }
    s += __shfl_xor(s, 1);
    s += __shfl_xor(s, 2);
    if (q == 0) e2[j] = s;
}

// ---------------------------------------------------------------------------
// Fused bf16-split MFMA GEMM + argmin.
// S = Ahi*Bhi + Alo*Bhi + Ahi*Blo (3 phases x 8 panels of K=32).
// Block 128x128 (4 waves, 2x2, each 64x64 via 4x4 frags of 16x16x32).
// Staged in MFMA fragment order via global_load_lds (16B/lane).
// d = e2[n] - 2*S; argmin via sortable u64 key (tie -> lowest n).
// ---------------------------------------------------------------------------
__global__ __launch_bounds__(256) void mfma_argmin(
    const unsigned short* __restrict__ Ap, const unsigned short* __restrict__ Bp,
    const float* __restrict__ e2, u64* __restrict__ amin) {
    __shared__ unsigned short Abuf[8 * 512];   // 8 frag-chunks x (16 rows x 32 k)
    __shared__ unsigned short Bbuf[8 * 512];

    const int tid = threadIdx.x;
    const int lane = tid & 63;
    const int wid = tid >> 6;
    const int c16 = lane & 15, q = lane >> 4;
    const int n0 = blockIdx.x * 128, m0 = blockIdx.y * 128;
    const int wm = wid >> 1, wn = wid & 1;

    // Staging assignment: waves 0-1 -> A chunks 0-7, waves 2-3 -> B chunks 0-7.
    const unsigned short* gb[4];
    unsigned short* lb[4];
    bool isA[4];
    #pragma unroll
    for (int c = 0; c < 4; ++c) {
        const int chunk = wid * 4 + c;
        const bool a = chunk < 8;
        const int f = a ? chunk : chunk - 8;
        const int row = (a ? m0 : n0) + f * 16 + c16;
        gb[c] = (a ? Ap : Bp) + (size_t)row * KP + q * 8;
        lb[c] = (a ? Abuf : Bbuf) + f * 512;
        isA[c] = a;
    }

    const f32x4 zero4 = {0.f, 0.f, 0.f, 0.f};
    f32x4 acc[4][4];
    #pragma unroll
    for (int i = 0; i < 4; ++i)
        #pragma unroll
        for (int j = 0; j < 4; ++j) acc[i][j] = zero4;

    float e2v[4];
    #pragma unroll
    for (int j = 0; j < 4; ++j) e2v[j] = e2[n0 + wn * 64 + j * 16 + c16];

    #pragma unroll
    for (int ph = 0; ph < 3; ++ph) {
        const int ka = (ph == 1) ? 256 : 0;   // A: hi, lo, hi
        const int kb = (ph == 2) ? 256 : 0;   // B: hi, hi, lo
        for (int p = 0; p < 8; ++p) {
            __syncthreads();   // previous panel fully consumed
            const int kA = ka + p * 32, kB = kb + p * 32;
            #pragma unroll
            for (int c = 0; c < 4; ++c)
                gl_lds16(gb[c] + (isA[c] ? kA : kB), lb[c]);
            __syncthreads();   // staging complete (vmcnt drained by barrier)
            bf16x8 av[4], bv[4];
            #pragma unroll
            for (int i = 0; i < 4; ++i)
                av[i] = *(const bf16x8*)(Abuf + (wm * 4 + i) * 512 + lane * 8);
            #pragma unroll
            for (int j = 0; j < 4; ++j)
                bv[j] = *(const bf16x8*)(Bbuf + (wn * 4 + j) * 512 + lane * 8);
            #pragma unroll
            for (int i = 0; i < 4; ++i)
                #pragma unroll
                for (int j = 0; j < 4; ++j)
                    acc[i][j] = __builtin_amdgcn_mfma_f32_16x16x32_bf16(
                        av[i], bv[j], acc[i][j], 0, 0, 0);
        }
    }

    // Epilogue: d = e2 - 2S; sortable key = monotone(f32) << 32 | n_global.
    u64 key[4][4];   // [i][r] over this lane's 16 m-positions, min over j
    #pragma unroll
    for (int i = 0; i < 4; ++i)
        #pragma unroll
        for (int r = 0; r < 4; ++r) key[i][r] = ~0ull;
    #pragma unroll
    for (int i = 0; i < 4; ++i)
        #pragma unroll
        for (int j = 0; j < 4; ++j) {
            const unsigned int n = n0 + wn * 64 + j * 16 + c16;
            #pragma unroll
            for (int r = 0; r < 4; ++r) {
                const float d = e2v[j] - 2.0f * acc[i][j][r];
                unsigned int u = __float_as_uint(d);
                u = (u & 0x80000000u) ? ~u : (u | 0x80000000u);
                const u64 k64 = ((u64)u << 32) | n;
                if (k64 < key[i][r]) key[i][r] = k64;
            }
        }
    // Butterfly min over the 16 n-lanes (c16).
    #pragma unroll
    for (int s = 1; s < 16; s <<= 1)
        #pragma unroll
        for (int i = 0; i < 4; ++i)
            #pragma unroll
            for (int r = 0; r < 4; ++r) {
                const u64 o = __shfl_xor(key[i][r], s);
                if (o < key[i][r]) key[i][r] = o;
            }

    __syncthreads();                       // done with Abuf; reuse as red[128][2]
    u64* red = (u64*)Abuf;
    if (c16 == 0) {
        #pragma unroll
        for (int i = 0; i < 4; ++i)
            #pragma unroll
            for (int r = 0; r < 4; ++r)
                red[(wm * 64 + i * 16 + q * 4 + r) * 2 + wn] = key[i][r];
    }
    __syncthreads();
    if (tid < 128) {
        const u64 a = red[tid * 2], b = red[tid * 2 + 1];
        atomicMin(&amin[m0 + tid], a < b ? a : b);
    }
}

// ---------------------------------------------------------------------------
// Finalize: unpack idx; emit total_idx (4 stacked copies, as float).
// ---------------------------------------------------------------------------
__global__ __launch_bounds__(256) void finalize_out(
    const u64* __restrict__ amin, int* __restrict__ idxf,
    float* __restrict__ out_idx) {
    const int n = blockIdx.x * 256 + threadIdx.x;
    const int bi = (int)(unsigned int)(amin[n] & 0xFFFFFFFFull);
    idxf[n] = bi;
    const int b = n >> 10, hw = n & 1023;
    const float fv = (float)bi;
    #pragma unroll
    for (int s = 0; s < 4; ++s) out_idx[b * 4096 + s * 1024 + hw] = fv;
}

// ---------------------------------------------------------------------------
// Gather q = emb[idx]; z_hat_out = z + (4q - z); loss accumulation.
// ---------------------------------------------------------------------------
__global__ __launch_bounds__(256) void quant_loss(
    const float* __restrict__ z, const float* __restrict__ emb,
    const int* __restrict__ idxf, float* __restrict__ out,
    float* __restrict__ loss) {
    __shared__ int idx_l[32];
    __shared__ float wsum[4];
    const int b = blockIdx.z;
    const int c0 = blockIdx.y * 8;
    const int hw0 = blockIdx.x * 32;
    const int t = threadIdx.x;
    const int hw_l = t & 31;
    const int c_l = t >> 5;
    if (t < 32) idx_l[t] = idxf[b * 1024 + hw0 + t];
    __syncthreads();
    const int j = idx_l[hw_l];
    const float qv = emb[(size_t)j * D + c0 + c_l];
    const size_t zi = (size_t)b * 262144 + (size_t)(c0 + c_l) * 1024 + hw0 + hw_l;
    const float zv = z[zi];
    const float zh = ((qv + qv) + qv) + qv;
    out[zi] = zv + (zh - zv);
    float e = 30.0f * qv * qv - 20.0f * qv * zv + 4.0f * zv * zv;
    #pragma unroll
    for (int off = 32; off > 0; off >>= 1) e += __shfl_down(e, off);
    if ((t & 63) == 0) wsum[t >> 6] = e;
    __syncthreads();
    if (t == 0) {
        const float s = wsum[0] + wsum[1] + wsum[2] + wsum[3];
        atomicAdd(loss, s * (0.3125f / 2097152.0f));
    }
}

// ---------------------------------------------------------------------------
extern "C" void kernel_launch(void* const* d_in, const int* in_sizes, int n_in,
                              void* d_out, int out_size, void* d_ws, size_t ws_size,
                              hipStream_t stream) {
    const float* z = (const float*)d_in[0];     // [8,256,32,32]
    const float* emb = (const float*)d_in[1];   // [16384,256]
    float* out = (float*)d_out;                 // z_hat_out | loss | total_idx

    // Workspace layout (~25.3 MB)
    unsigned short* Ap = (unsigned short*)d_ws;          // 8192*512 bf16
    unsigned short* Bp = Ap + (size_t)NPTS * KP;         // 16384*512 bf16
    float* e2 = (float*)(Bp + (size_t)N_E * KP);         // 16384 f
    u64* amin = (u64*)(e2 + N_E);                        // 8192 u64
    int* idxf = (int*)(amin + NPTS);                     // 8192 i

    float* loss = out + ZOUT;
    float* out_idx = out + ZOUT + 1;

    hipMemsetAsync(loss, 0, sizeof(float), stream);
    hipMemsetAsync(amin, 0xFF, NPTS * sizeof(u64), stream);
    prep_a<<<NPTS / 64, 256, 0, stream>>>(z, Ap);
    prep_b<<<N_E / 64, 256, 0, stream>>>(emb, Bp, e2);
    mfma_argmin<<<dim3(N_E / 128, NPTS / 128), 256, 0, stream>>>(Ap, Bp, e2, amin);
    finalize_out<<<NPTS / 256, 256, 0, stream>>>(amin, idxf, out_idx);
    quant_loss<<<dim3(32, 32, 8), 256, 0, stream>>>(z, emb, idxf, out, loss);
}

// Round 3
// 321.569 us; speedup vs baseline: 3.6840x; 1.9201x over previous
//
#include <hip/hip_runtime.h>

// Problem constants (fixed by the reference).
#define D      256        // vq_embed_dim == C
#define N_E    16384      // codebook size
#define NPTS   8192       // B*H*W
#define ZOUT   2097152    // elements of z_hat_out
#define MARGIN 2.0e-2f    // 2*eps rescan margin; bf16-hi GEMM d-error sigma ~1.5e-3

typedef short bf16x8 __attribute__((ext_vector_type(8)));
typedef float f32x16 __attribute__((ext_vector_type(16)));
typedef unsigned long long u64;

__device__ __forceinline__ unsigned short f2bf(float x) {  // RNE
    unsigned int u = __float_as_uint(x);
    return (unsigned short)((u + 0x7FFFu + ((u >> 16) & 1u)) >> 16);
}
__device__ __forceinline__ void gl_lds16(const void* g, void* l) {
    __builtin_amdgcn_global_load_lds(
        (const __attribute__((address_space(1))) unsigned int*)g,
        (__attribute__((address_space(3))) unsigned int*)l, 16, 0, 0);
}

// ---------------------------------------------------------------------------
// Prep A: z[b,k,hw] -> Ahi[n][256] bf16, Af32[n][256] fp32 (n = b*1024+hw).
// ---------------------------------------------------------------------------
__global__ __launch_bounds__(256) void prep_a(const float* __restrict__ z,
                                              unsigned short* __restrict__ Ahi,
                                              float* __restrict__ Af32) {
    const int t = threadIdx.x;
    const int lane = t & 63, kg = t >> 6;   // kg 0..3
    const int n0 = blockIdx.x * 64;
    const int b = n0 >> 10, hw0 = n0 & 1023;
    const float* zb = z + (size_t)b * 262144 + hw0 + lane;
    const int n = n0 + lane;
    #pragma unroll
    for (int i = 0; i < 16; ++i) {
        const int k0 = i * 16 + kg * 4;
        float4 vf;
        ushort4 hv;
        float* vp = (float*)&vf;
        unsigned short* hp = (unsigned short*)&hv;
        #pragma unroll
        for (int j = 0; j < 4; ++j) {
            const float v = zb[(size_t)(k0 + j) * 1024];   // coalesced in lane
            vp[j] = v;
            hp[j] = f2bf(v);
        }
        *(ushort4*)(Ahi + (size_t)n * D + k0) = hv;
        *(float4*)(Af32 + (size_t)n * D + k0) = vf;
    }
}

// ---------------------------------------------------------------------------
// Prep B: emb -> Bhi[j][256] bf16; e2[j] = |emb_j|^2 (fp32 exact).
// ---------------------------------------------------------------------------
__global__ __launch_bounds__(256) void prep_b(const float* __restrict__ emb,
                                              unsigned short* __restrict__ Bhi,
                                              float* __restrict__ e2) {
    const int t = threadIdx.x;
    const int j = blockIdx.x * 64 + (t >> 2);
    const int q = t & 3;                     // k-quarter
    const float* row = emb + (size_t)j * D + q * 64;
    unsigned short* oh = Bhi + (size_t)j * D + q * 64;
    float s = 0.f;
    #pragma unroll
    for (int i = 0; i < 16; ++i) {
        const float4 v = *(const float4*)(row + i * 4);
        s += v.x * v.x + v.y * v.y + v.z * v.z + v.w * v.w;
        const float vv[4] = {v.x, v.y, v.z, v.w};
        ushort4 hv;
        unsigned short* hp = (unsigned short*)&hv;
        #pragma unroll
        for (int c = 0; c < 4; ++c) hp[c] = f2bf(vv[c]);
        *(ushort4*)(oh + i * 4) = hv;
    }
    s += __shfl_xor(s, 1);
    s += __shfl_xor(s, 2);
    if (q == 0) e2[j] = s;
}

// ---------------------------------------------------------------------------
// Pass 1: hi-only bf16 GEMM (K=256) with 32x32x16 MFMA, 128x128 tile,
// BK=128 (2 panels). Emits per (point, 32-code-group) min of
// d~ = e2[j] - 2*S~  into tmin[n][512] (f32, no atomics).
// C/D layout (m74/m101): col=lane&31, row=(r&3)+8*(r>>2)+4*(lane>>5).
// ---------------------------------------------------------------------------
__global__ __launch_bounds__(256, 2) void mfma_hi32(
    const unsigned short* __restrict__ Ahi, const unsigned short* __restrict__ Bhi,
    const float* __restrict__ e2, float* __restrict__ tmin) {
    __shared__ __align__(16) unsigned char smem[66048];
    unsigned short* Abuf = (unsigned short*)smem;            // 32 chunks x 1KB
    unsigned short* Bbuf = (unsigned short*)(smem + 32768);  // 32 chunks x 1KB
    float* dbuf = (float*)smem;                              // [128][129] f32

    const int tid = threadIdx.x;
    const int lane = tid & 63, wid = tid >> 6;
    const int c32 = lane & 31, l5 = lane >> 5;
    const int n0 = blockIdx.x * 128, m0 = blockIdx.y * 128;
    const int wm = wid >> 1, wn = wid & 1;

    // Staging assignment: waves 0,1 -> A row-groups {0,1},{2,3}; waves 2,3 -> B.
    const unsigned short* gsrc = (wid < 2) ? Ahi : Bhi;
    unsigned short* lbase = (wid < 2) ? Abuf : Bbuf;
    const int rg0 = (wid & 1) * 2;
    const int base_row = (wid < 2) ? m0 : n0;

    const f32x16 z16 = {0.f};
    f32x16 acc[2][2];
    acc[0][0] = z16; acc[0][1] = z16; acc[1][0] = z16; acc[1][1] = z16;

    for (int p = 0; p < 2; ++p) {
        __syncthreads();                    // previous panel fully consumed
        const int kp = p * 128;
        #pragma unroll
        for (int rg = 0; rg < 2; ++rg)
            #pragma unroll
            for (int ks = 0; ks < 8; ++ks)
                gl_lds16(gsrc + (size_t)(base_row + (rg0 + rg) * 32 + c32) * D
                              + kp + ks * 16 + l5 * 8,
                         lbase + ((rg0 + rg) * 8 + ks) * 512);
        __syncthreads();                    // staging visible (vmcnt drained)
        #pragma unroll
        for (int s = 0; s < 8; ++s) {
            const bf16x8 a0 = *(const bf16x8*)(Abuf + ((wm * 2 + 0) * 8 + s) * 512 + lane * 8);
            const bf16x8 a1 = *(const bf16x8*)(Abuf + ((wm * 2 + 1) * 8 + s) * 512 + lane * 8);
            const bf16x8 b0 = *(const bf16x8*)(Bbuf + ((wn * 2 + 0) * 8 + s) * 512 + lane * 8);
            const bf16x8 b1 = *(const bf16x8*)(Bbuf + ((wn * 2 + 1) * 8 + s) * 512 + lane * 8);
            acc[0][0] = __builtin_amdgcn_mfma_f32_32x32x16_bf16(a0, b0, acc[0][0], 0, 0, 0);
            acc[0][1] = __builtin_amdgcn_mfma_f32_32x32x16_bf16(a0, b1, acc[0][1], 0, 0, 0);
            acc[1][0] = __builtin_amdgcn_mfma_f32_32x32x16_bf16(a1, b0, acc[1][0], 0, 0, 0);
            acc[1][1] = __builtin_amdgcn_mfma_f32_32x32x16_bf16(a1, b1, acc[1][1], 0, 0, 0);
        }
    }

    float e2v[2];
    e2v[0] = e2[n0 + wn * 64 + c32];
    e2v[1] = e2[n0 + wn * 64 + 32 + c32];

    __syncthreads();        // all waves done reading Abuf/Bbuf; reuse as dbuf
    #pragma unroll
    for (int i = 0; i < 2; ++i)
        #pragma unroll
        for (int j = 0; j < 2; ++j) {
            #pragma unroll
            for (int r = 0; r < 16; ++r) {
                const int row = wm * 64 + i * 32 + (r & 3) + 8 * (r >> 2) + 4 * l5;
                const int col = wn * 64 + j * 32 + c32;
                dbuf[row * 129 + col] = e2v[j] - 2.0f * acc[i][j][r];
            }
        }
    __syncthreads();
    // Reduce each (row, 32-col group) -> tmin. Thread t: row=t&127, 2 groups.
    {
        const int row = tid & 127;
        const int gp = tid >> 7;
        #pragma unroll
        for (int gg = 0; gg < 2; ++gg) {
            const int g = gp * 2 + gg;
            const float* dr = dbuf + row * 129 + g * 32;
            float m = dr[0];
            #pragma unroll
            for (int c = 1; c < 32; ++c) m = fminf(m, dr[c]);
            tmin[(size_t)(m0 + row) * 512 + blockIdx.x * 4 + g] = m;
        }
    }
}

// ---------------------------------------------------------------------------
// Pass 2: per point, m1 = min over 512 group-mins; exact fp32 rescan of every
// group with gmin <= m1 + MARGIN (true argmin's group provably qualifies);
// tie -> lowest j (np.argmin first occurrence). One wave per point.
// Emits idxf and total_idx (4 stacked copies, as float).
// ---------------------------------------------------------------------------
__global__ __launch_bounds__(256) void rescore(
    const float* __restrict__ tmin, const float* __restrict__ Af32,
    const float* __restrict__ emb, const float* __restrict__ e2,
    int* __restrict__ idxf, float* __restrict__ out_idx) {
    __shared__ float rbuf[4][256];
    const int tid = threadIdx.x, lane = tid & 63, w = tid >> 6;
    const int n = blockIdx.x * 4 + w;
    const int c32 = lane & 31, h = lane >> 5;

    *(float4*)&rbuf[w][lane * 4] = *(const float4*)(Af32 + (size_t)n * D + lane * 4);
    __syncthreads();

    float tv[8];
    #pragma unroll
    for (int gi = 0; gi < 8; ++gi) tv[gi] = tmin[(size_t)n * 512 + gi * 64 + lane];
    float m1 = tv[0];
    #pragma unroll
    for (int gi = 1; gi < 8; ++gi) m1 = fminf(m1, tv[gi]);
    #pragma unroll
    for (int st = 1; st < 64; st <<= 1) m1 = fminf(m1, __shfl_xor(m1, st));
    const float thresh = m1 + MARGIN;

    u64 best = ~0ull;
    const float* rr = &rbuf[w][h * 128];
    for (int gi = 0; gi < 8; ++gi) {
        u64 mask = __ballot(tv[gi] <= thresh);
        while (mask) {
            const int bit = (int)__builtin_ctzll(mask);
            mask &= mask - 1;
            const int g = gi * 64 + bit;
            const int c = g * 32 + c32;           // this lane's code
            const float* er = emb + (size_t)c * D + h * 128;
            float s = 0.f;
            #pragma unroll
            for (int k = 0; k < 32; ++k) {
                const float4 ev = *(const float4*)(er + k * 4);
                s += rr[k * 4 + 0] * ev.x + rr[k * 4 + 1] * ev.y +
                     rr[k * 4 + 2] * ev.z + rr[k * 4 + 3] * ev.w;
            }
            s += __shfl_xor(s, 32);               // combine k-halves
            const float d = e2[c] - 2.0f * s;
            unsigned int u = __float_as_uint(d);
            u = (u & 0x80000000u) ? ~u : (u | 0x80000000u);
            const u64 key = ((u64)u << 32) | (unsigned int)c;
            if (key < best) best = key;
        }
    }
    #pragma unroll
    for (int st = 1; st < 32; st <<= 1) {
        const u64 o = __shfl_xor(best, st);
        if (o < best) best = o;
    }
    if (lane == 0) {
        const int bi = (int)(unsigned int)(best & 0xFFFFFFFFull);
        idxf[n] = bi;
        const int b = n >> 10, hw = n & 1023;
        const float fv = (float)bi;
        #pragma unroll
        for (int sc = 0; sc < 4; ++sc) out_idx[b * 4096 + sc * 1024 + hw] = fv;
    }
}

// ---------------------------------------------------------------------------
// Gather q = emb[idx]; z_hat_out = z + (4q - z); loss accumulation.
// 256 blocks: block = (b, 32-wide hw tile) x all 256 channels.
// ---------------------------------------------------------------------------
__global__ __launch_bounds__(256) void quant_loss(
    const float* __restrict__ z, const float* __restrict__ emb,
    const int* __restrict__ idxf, float* __restrict__ out,
    float* __restrict__ loss) {
    __shared__ int idx_l[32];
    __shared__ float wsum[4];
    const int blk = blockIdx.x;
    const int b = blk >> 5, hw0 = (blk & 31) * 32;
    const int t = threadIdx.x, hw_l = t & 31, cg = t >> 5;
    if (t < 32) idx_l[t] = idxf[b * 1024 + hw0 + t];
    __syncthreads();
    const int j = idx_l[hw_l];
    float e = 0.f;
    for (int cc = 0; cc < 32; ++cc) {
        const int c = cg * 32 + cc;
        const float q = emb[(size_t)j * D + c];
        const size_t zi = (size_t)b * 262144 + (size_t)c * 1024 + hw0 + hw_l;
        const float zv = z[zi];
        const float zh = ((q + q) + q) + q;   // mimic 4-step accumulation
        out[zi] = zv + (zh - zv);
        e += 30.0f * q * q - 20.0f * q * zv + 4.0f * zv * zv;
    }
    #pragma unroll
    for (int off = 32; off > 0; off >>= 1) e += __shfl_down(e, off);
    if ((t & 63) == 0) wsum[t >> 6] = e;
    __syncthreads();
    if (t == 0) {
        const float s = wsum[0] + wsum[1] + wsum[2] + wsum[3];
        atomicAdd(loss, s * (0.3125f / 2097152.0f));
    }
}

// ---------------------------------------------------------------------------
extern "C" void kernel_launch(void* const* d_in, const int* in_sizes, int n_in,
                              void* d_out, int out_size, void* d_ws, size_t ws_size,
                              hipStream_t stream) {
    const float* z = (const float*)d_in[0];     // [8,256,32,32]
    const float* emb = (const float*)d_in[1];   // [16384,256]
    float* out = (float*)d_out;                 // z_hat_out | loss | total_idx

    // Workspace layout (~36.1 MB)
    unsigned short* Ahi = (unsigned short*)d_ws;            // 8192*256 bf16
    unsigned short* Bhi = Ahi + (size_t)NPTS * D;           // 16384*256 bf16
    float* Af32 = (float*)(Bhi + (size_t)N_E * D);          // 8192*256 f32
    float* e2 = Af32 + (size_t)NPTS * D;                    // 16384 f32
    float* tmin = e2 + N_E;                                 // 8192*512 f32
    int* idxf = (int*)(tmin + (size_t)NPTS * 512);          // 8192 i32

    float* loss = out + ZOUT;
    float* out_idx = out + ZOUT + 1;

    hipMemsetAsync(loss, 0, sizeof(float), stream);
    prep_a<<<NPTS / 64, 256, 0, stream>>>(z, Ahi, Af32);
    prep_b<<<N_E / 64, 256, 0, stream>>>(emb, Bhi, e2);
    mfma_hi32<<<dim3(N_E / 128, NPTS / 128), 256, 0, stream>>>(Ahi, Bhi, e2, tmin);
    rescore<<<NPTS / 4, 256, 0, stream>>>(tmin, Af32, emb, e2, idxf, out_idx);
    quant_loss<<<256, 256, 0, stream>>>(z, emb, idxf, out, loss);
}

// Round 4
// 265.455 us; speedup vs baseline: 4.4628x; 1.2114x over previous
//
#include <hip/hip_runtime.h>

// Problem constants (fixed by the reference).
#define D      256        // vq_embed_dim == C
#define N_E    16384      // codebook size
#define NPTS   8192       // B*H*W
#define ZOUT   2097152    // elements of z_hat_out
#define MARGIN 2.0e-2f    // rescan margin; bf16-hi GEMM d-error sigma ~1.5e-3

typedef short bf16x8 __attribute__((ext_vector_type(8)));
typedef unsigned short us8 __attribute__((ext_vector_type(8)));
typedef float f32x16 __attribute__((ext_vector_type(16)));
typedef unsigned long long u64;

__device__ __forceinline__ unsigned short f2bf(float x) {  // RNE
    unsigned int u = __float_as_uint(x);
    return (unsigned short)((u + 0x7FFFu + ((u >> 16) & 1u)) >> 16);
}
__device__ __forceinline__ void gl_lds16(const void* g, void* l) {
    __builtin_amdgcn_global_load_lds(
        (const __attribute__((address_space(1))) unsigned int*)g,
        (__attribute__((address_space(3))) unsigned int*)l, 16, 0, 0);
}

// ---------------------------------------------------------------------------
// Fused prep. Blocks [0,128): points. Blocks [128,384): codes.
// Zpk: bf16(-2*z) in fragment-chunk layout (chunk = (pg, ks) -> 64 lanes x 16B,
//      lane l = (row&31) + ((k>>3)&1)*32, elements k&7). Zf32: z transposed.
// Epk: bf16(emb) same chunk layout. e2: |emb_j|^2 fp32.
// ---------------------------------------------------------------------------
__global__ __launch_bounds__(256) void prep(
    const float* __restrict__ z, const float* __restrict__ emb,
    unsigned short* __restrict__ Zpk, float* __restrict__ Zf32,
    unsigned short* __restrict__ Epk, float* __restrict__ e2) {
    const int t = threadIdx.x;
    if (blockIdx.x < 128) {
        const int n0 = blockIdx.x * 64;
        const int lane = t & 63, kg = t >> 6;       // kg: 64-k slab
        const int n = n0 + lane;
        const int b = n >> 10, hw = n & 1023;
        const float* zb = z + (size_t)b * 262144 + hw;
        #pragma unroll
        for (int i = 0; i < 8; ++i) {
            const int k0 = kg * 64 + i * 8;
            float v[8];
            us8 hv;
            #pragma unroll
            for (int kk = 0; kk < 8; ++kk) {
                v[kk] = zb[(size_t)(k0 + kk) * 1024];   // coalesced in lane
                hv[kk] = f2bf(-2.0f * v[kk]);           // exact 2x scale
            }
            float4 f0 = {v[0], v[1], v[2], v[3]}, f1 = {v[4], v[5], v[6], v[7]};
            *(float4*)(Zf32 + (size_t)n * D + k0) = f0;
            *(float4*)(Zf32 + (size_t)n * D + k0 + 4) = f1;
            const int g = n >> 5, ks = k0 >> 4, l = (n & 31) + ((k0 >> 3) & 1) * 32;
            *(us8*)(Zpk + ((size_t)(g * 16 + ks) * 64 + l) * 8) = hv;
        }
    } else {
        const int j0 = (blockIdx.x - 128) * 64;
        const int jj = j0 + (t >> 2), q = t & 3;    // q: 64-k slab
        const float* row = emb + (size_t)jj * D + q * 64;
        float s = 0.f;
        #pragma unroll
        for (int i = 0; i < 8; ++i) {
            const int k0 = q * 64 + i * 8;
            const float4 v0 = *(const float4*)(row + i * 8);
            const float4 v1 = *(const float4*)(row + i * 8 + 4);
            s += v0.x * v0.x + v0.y * v0.y + v0.z * v0.z + v0.w * v0.w +
                 v1.x * v1.x + v1.y * v1.y + v1.z * v1.z + v1.w * v1.w;
            const float vv[8] = {v0.x, v0.y, v0.z, v0.w, v1.x, v1.y, v1.z, v1.w};
            us8 hv;
            #pragma unroll
            for (int c = 0; c < 8; ++c) hv[c] = f2bf(vv[c]);
            const int g = jj >> 5, ks = k0 >> 4, l = (jj & 31) + ((k0 >> 3) & 1) * 32;
            *(us8*)(Epk + ((size_t)(g * 16 + ks) * 64 + l) * 8) = hv;
        }
        s += __shfl_xor(s, 1);
        s += __shfl_xor(s, 2);
        if (q == 0) e2[jj] = s;
    }
}

// ---------------------------------------------------------------------------
// Barrier-free-K GEMM + group-min. C rows = codes (A-op = Epk, streamed to
// VGPR), C cols = points (B-op = Zpk staged once in LDS). Block: 256 codes x
// 128 points; 4 waves 2x2, wave tile 128 codes x 64 points (4x2 frags 32x32).
// acc = sum (-2z)*e; d = e2[code] + acc. tmin[point][code-group of 32] = min.
// ---------------------------------------------------------------------------
__global__ __launch_bounds__(256, 2) void mfma_gemm(
    const unsigned short* __restrict__ Epk, const unsigned short* __restrict__ Zpk,
    const float* __restrict__ e2, float* __restrict__ tmin) {
    __shared__ unsigned short Zbuf[64 * 512];   // 64 chunks x 1 KB = 64 KB

    const int tid = threadIdx.x, lane = tid & 63, wid = tid >> 6;
    const int c32 = lane & 31, l5 = lane >> 5;
    const int n0 = blockIdx.x * 128;            // points
    const int m0 = blockIdx.y * 256;            // codes
    const int wm = wid >> 1, wn = wid & 1;

    // Stage Z once: wave wid stages point-group (n0/32 + wid), all 16 k-steps.
    #pragma unroll
    for (int ks = 0; ks < 16; ++ks)
        gl_lds16(Zpk + ((size_t)((n0 >> 5) + wid) * 16 + ks) * 512 + lane * 8,
                 Zbuf + (wid * 16 + ks) * 512);
    __syncthreads();   // single drain for the whole block

    f32x16 acc[4][2];
    const f32x16 z16 = {0.f};
    #pragma unroll
    for (int i = 0; i < 4; ++i) { acc[i][0] = z16; acc[i][1] = z16; }

    const unsigned short* ebase =
        Epk + ((size_t)((m0 >> 5) + wm * 4) * 16) * 512 + lane * 8;
    const unsigned short* zbase = Zbuf + (wn * 2) * 16 * 512 + lane * 8;

    #pragma unroll 4
    for (int ks = 0; ks < 16; ++ks) {
        bf16x8 ef[4], pf[2];
        #pragma unroll
        for (int i = 0; i < 4; ++i)
            ef[i] = *(const bf16x8*)(ebase + (size_t)(i * 16 + ks) * 512);
        #pragma unroll
        for (int j = 0; j < 2; ++j)
            pf[j] = *(const bf16x8*)(zbase + (j * 16 + ks) * 512);
        #pragma unroll
        for (int i = 0; i < 4; ++i)
            #pragma unroll
            for (int j = 0; j < 2; ++j)
                acc[i][j] = __builtin_amdgcn_mfma_f32_32x32x16_bf16(
                    ef[i], pf[j], acc[i][j], 0, 0, 0);
    }

    // Epilogue: per code-frag i, min over its 32 code-rows per point-lane.
    #pragma unroll
    for (int i = 0; i < 4; ++i) {
        const int cbase = m0 + wm * 128 + i * 32;
        float e2r[16];
        #pragma unroll
        for (int r = 0; r < 16; ++r)
            e2r[r] = e2[cbase + (r & 3) + 8 * (r >> 2) + 4 * l5];
        #pragma unroll
        for (int j = 0; j < 2; ++j) {
            float m = e2r[0] + acc[i][j][0];
            #pragma unroll
            for (int r = 1; r < 16; ++r) m = fminf(m, e2r[r] + acc[i][j][r]);
            m = fminf(m, __shfl_xor(m, 32));    // fold the two l5 row-halves
            if (l5 == 0)
                tmin[(size_t)(n0 + wn * 64 + j * 32 + c32) * 512 + (cbase >> 5)] = m;
        }
    }
}

// ---------------------------------------------------------------------------
// Rescore: m1 = min over 512 group-mins; exact fp32 rescan of groups with
// gmin <= m1 + MARGIN; tie -> lowest j. Emits idxf + total_idx. Zeroes loss.
// ---------------------------------------------------------------------------
__global__ __launch_bounds__(256) void rescore(
    const float* __restrict__ tmin, const float* __restrict__ Zf32,
    const float* __restrict__ emb, const float* __restrict__ e2,
    int* __restrict__ idxf, float* __restrict__ out_idx,
    float* __restrict__ loss) {
    __shared__ float rbuf[4][256];
    const int tid = threadIdx.x, lane = tid & 63, w = tid >> 6;
    const int n = blockIdx.x * 4 + w;
    const int c32 = lane & 31, h = lane >> 5;
    if (blockIdx.x == 0 && tid == 0) loss[0] = 0.f;

    *(float4*)&rbuf[w][lane * 4] = *(const float4*)(Zf32 + (size_t)n * D + lane * 4);
    __syncthreads();

    float tv[8];
    #pragma unroll
    for (int gi = 0; gi < 8; ++gi) tv[gi] = tmin[(size_t)n * 512 + gi * 64 + lane];
    float m1 = tv[0];
    #pragma unroll
    for (int gi = 1; gi < 8; ++gi) m1 = fminf(m1, tv[gi]);
    #pragma unroll
    for (int st = 1; st < 64; st <<= 1) m1 = fminf(m1, __shfl_xor(m1, st));
    const float thresh = m1 + MARGIN;

    u64 best = ~0ull;
    const float* rr = &rbuf[w][h * 128];
    for (int gi = 0; gi < 8; ++gi) {
        u64 mask = __ballot(tv[gi] <= thresh);
        while (mask) {
            const int bit = (int)__builtin_ctzll(mask);
            mask &= mask - 1;
            const int g = gi * 64 + bit;
            const int c = g * 32 + c32;
            const float* er = emb + (size_t)c * D + h * 128;
            float s = 0.f;
            #pragma unroll
            for (int k = 0; k < 32; ++k) {
                const float4 ev = *(const float4*)(er + k * 4);
                s += rr[k * 4 + 0] * ev.x + rr[k * 4 + 1] * ev.y +
                     rr[k * 4 + 2] * ev.z + rr[k * 4 + 3] * ev.w;
            }
            s += __shfl_xor(s, 32);
            const float d = e2[c] - 2.0f * s;
            unsigned int u = __float_as_uint(d);
            u = (u & 0x80000000u) ? ~u : (u | 0x80000000u);
            const u64 key = ((u64)u << 32) | (unsigned int)c;
            if (key < best) best = key;
        }
    }
    #pragma unroll
    for (int st = 1; st < 32; st <<= 1) {
        const u64 o = __shfl_xor(best, st);
        if (o < best) best = o;
    }
    if (lane == 0) {
        const int bi = (int)(unsigned int)(best & 0xFFFFFFFFull);
        idxf[n] = bi;
        const int b = n >> 10, hw = n & 1023;
        const float fv = (float)bi;
        #pragma unroll
        for (int sc = 0; sc < 4; ++sc) out_idx[b * 4096 + sc * 1024 + hw] = fv;
    }
}

// ---------------------------------------------------------------------------
// Gather q = emb[idx]; z_hat_out = z + (4q - z); loss accumulation.
// ---------------------------------------------------------------------------
__global__ __launch_bounds__(256) void quant_loss(
    const float* __restrict__ z, const float* __restrict__ emb,
    const int* __restrict__ idxf, float* __restrict__ out,
    float* __restrict__ loss) {
    __shared__ int idx_l[32];
    __shared__ float wsum[4];
    const int blk = blockIdx.x;
    const int b = blk >> 5, hw0 = (blk & 31) * 32;
    const int t = threadIdx.x, hw_l = t & 31, cg = t >> 5;
    if (t < 32) idx_l[t] = idxf[b * 1024 + hw0 + t];
    __syncthreads();
    const int j = idx_l[hw_l];
    float e = 0.f;
    for (int cc = 0; cc < 32; ++cc) {
        const int c = cg * 32 + cc;
        const float q = emb[(size_t)j * D + c];
        const size_t zi = (size_t)b * 262144 + (size_t)c * 1024 + hw0 + hw_l;
        const float zv = z[zi];
        const float zh = ((q + q) + q) + q;   // mimic 4-step accumulation
        out[zi] = zv + (zh - zv);
        e += 30.0f * q * q - 20.0f * q * zv + 4.0f * zv * zv;
    }
    #pragma unroll
    for (int off = 32; off > 0; off >>= 1) e += __shfl_down(e, off);
    if ((t & 63) == 0) wsum[t >> 6] = e;
    __syncthreads();
    if (t == 0) {
        const float s = wsum[0] + wsum[1] + wsum[2] + wsum[3];
        atomicAdd(loss, s * (0.3125f / 2097152.0f));
    }
}

// ---------------------------------------------------------------------------
extern "C" void kernel_launch(void* const* d_in, const int* in_sizes, int n_in,
                              void* d_out, int out_size, void* d_ws, size_t ws_size,
                              hipStream_t stream) {
    const float* z = (const float*)d_in[0];     // [8,256,32,32]
    const float* emb = (const float*)d_in[1];   // [16384,256]
    float* out = (float*)d_out;                 // z_hat_out | loss | total_idx

    // Workspace (~36.1 MB)
    unsigned short* Zpk = (unsigned short*)d_ws;            // 8192*256 bf16
    unsigned short* Epk = Zpk + (size_t)NPTS * D;           // 16384*256 bf16
    float* Zf32 = (float*)(Epk + (size_t)N_E * D);          // 8192*256 f32
    float* e2 = Zf32 + (size_t)NPTS * D;                    // 16384 f32
    float* tmin = e2 + N_E;                                 // 8192*512 f32
    int* idxf = (int*)(tmin + (size_t)NPTS * 512);          // 8192 i32

    float* loss = out + ZOUT;
    float* out_idx = out + ZOUT + 1;

    prep<<<384, 256, 0, stream>>>(z, emb, Zpk, Zf32, Epk, e2);
    mfma_gemm<<<dim3(NPTS / 128, N_E / 256), 256, 0, stream>>>(Epk, Zpk, e2, tmin);
    rescore<<<NPTS / 4, 256, 0, stream>>>(tmin, Zf32, emb, e2, idxf, out_idx, loss);
    quant_loss<<<256, 256, 0, stream>>>(z, emb, idxf, out, loss);
}

// Round 5
// 242.389 us; speedup vs baseline: 4.8874x; 1.0952x over previous
//
#include <hip/hip_runtime.h>

// Problem constants (fixed by the reference).
#define D      256        // vq_embed_dim == C
#define N_E    16384      // codebook size
#define NPTS   8192       // B*H*W
#define ZOUT   2097152    // elements of z_hat_out
#define MARGIN 2.0e-2f    // rescan margin; bf16-hi GEMM d-error ~7 sigma
#define STRIPS 4          // 256-code strips per block

typedef short bf16x8 __attribute__((ext_vector_type(8)));
typedef unsigned short us8 __attribute__((ext_vector_type(8)));
typedef float f32x16 __attribute__((ext_vector_type(16)));
typedef unsigned long long u64;

__device__ __forceinline__ unsigned short f2bf(float x) {  // RNE
    unsigned int u = __float_as_uint(x);
    return (unsigned short)((u + 0x7FFFu + ((u >> 16) & 1u)) >> 16);
}
__device__ __forceinline__ void gl_lds16(const void* g, void* l) {
    __builtin_amdgcn_global_load_lds(
        (const __attribute__((address_space(1))) unsigned int*)g,
        (__attribute__((address_space(3))) unsigned int*)l, 16, 0, 0);
}

// ---------------------------------------------------------------------------
// Fused prep. Blocks [0,256): z (32 points each). Blocks [256,768): emb
// (32 codes each). Zpk = bf16(-2z), Epk = bf16(emb), both in MFMA fragment-
// chunk layout (chunk (g,ks): 64 lanes x 16B, lane l = (row&31)+((k>>3)&1)*32).
// Zf32 = z transposed to [n][k]. e2[j] = |emb_j|^2 fp32.
// ---------------------------------------------------------------------------
__global__ __launch_bounds__(256) void prep(
    const float* __restrict__ z, const float* __restrict__ emb,
    unsigned short* __restrict__ Zpk, float* __restrict__ Zf32,
    unsigned short* __restrict__ Epk, float* __restrict__ e2) {
    const int t = threadIdx.x;
    if (blockIdx.x < 256) {
        const int n0 = blockIdx.x * 32;
        const int p = t & 31, ks8 = t >> 5;     // 8 k-slabs of 32
        const int n = n0 + p;
        const int b = n >> 10, hw = n & 1023;
        const float* zb = z + (size_t)b * 262144 + hw;
        const int k0 = ks8 * 32;
        float v[32];
        #pragma unroll
        for (int kk = 0; kk < 32; ++kk)
            v[kk] = zb[(size_t)(k0 + kk) * 1024];   // coalesced in p
        #pragma unroll
        for (int i = 0; i < 8; ++i) {
            float4 f = {v[i * 4], v[i * 4 + 1], v[i * 4 + 2], v[i * 4 + 3]};
            *(float4*)(Zf32 + (size_t)n * D + k0 + i * 4) = f;
        }
        const int g = n >> 5;
        #pragma unroll
        for (int i = 0; i < 4; ++i) {               // 4 us8 per 32-k slab
            us8 hv;
            #pragma unroll
            for (int c = 0; c < 8; ++c) hv[c] = f2bf(-2.0f * v[i * 8 + c]);
            const int kabs = k0 + i * 8;
            const int ks = kabs >> 4;
            const int l = (n & 31) + ((kabs >> 3) & 1) * 32;
            *(us8*)(Zpk + ((size_t)(g * 16 + ks) * 64 + l) * 8) = hv;
        }
    } else {
        const int j0 = (blockIdx.x - 256) * 32;
        const int jj = j0 + (t >> 3), q = t & 7;    // 8 k-slabs of 32
        const float* row = emb + (size_t)jj * D + q * 32;
        float v[32];
        float s = 0.f;
        #pragma unroll
        for (int i = 0; i < 8; ++i) {
            const float4 x = *(const float4*)(row + i * 4);
            v[i * 4] = x.x; v[i * 4 + 1] = x.y; v[i * 4 + 2] = x.z; v[i * 4 + 3] = x.w;
            s += x.x * x.x + x.y * x.y + x.z * x.z + x.w * x.w;
        }
        const int g = jj >> 5;
        #pragma unroll
        for (int i = 0; i < 4; ++i) {
            us8 hv;
            #pragma unroll
            for (int c = 0; c < 8; ++c) hv[c] = f2bf(v[i * 8 + c]);
            const int kabs = q * 32 + i * 8;
            const int ks = kabs >> 4;
            const int l = (jj & 31) + ((kabs >> 3) & 1) * 32;
            *(us8*)(Epk + ((size_t)(g * 16 + ks) * 64 + l) * 8) = hv;
        }
        s += __shfl_xor(s, 1);
        s += __shfl_xor(s, 2);
        s += __shfl_xor(s, 4);
        if (q == 0) e2[jj] = s;
    }
}

// ---------------------------------------------------------------------------
// GEMM + group-min. Block: 128 points (LDS, staged once) x STRIPS*256 codes.
// 4 waves; wave wid owns a DISTINCT 64-code column (no E duplication), all
// 128 points. Wave frags: 2 code x 4 point of 32x32x16; ef from global
// (fragment-contiguous chunks), pf from LDS; ks+1 register prefetch.
// d~ = e2[code] + acc (Zpk holds -2z). tmin[point][code>>5] = min over 32.
// ---------------------------------------------------------------------------
__global__ __launch_bounds__(256, 2) void mfma_gemm(
    const unsigned short* __restrict__ Epk, const unsigned short* __restrict__ Zpk,
    const float* __restrict__ e2, float* __restrict__ tmin) {
    __shared__ unsigned short Zbuf[64 * 512];   // 64 KB

    const int tid = threadIdx.x, lane = tid & 63, wid = tid >> 6;
    const int c32 = lane & 31, l5 = lane >> 5;
    const int n0 = blockIdx.x * 128;
    const int cs0 = blockIdx.y * (STRIPS * 256);

    #pragma unroll
    for (int ks = 0; ks < 16; ++ks)
        gl_lds16(Zpk + ((size_t)((n0 >> 5) + wid) * 16 + ks) * 512 + lane * 8,
                 Zbuf + (wid * 16 + ks) * 512);
    __syncthreads();   // single drain per block

    for (int s = 0; s < STRIPS; ++s) {
        const int cb = cs0 + s * 256 + wid * 64;   // this wave's 64 codes
        const unsigned short* eb = Epk + ((size_t)(cb >> 5) * 16) * 512 + lane * 8;
        const unsigned short* zb = Zbuf + lane * 8;

        f32x16 acc[2][4];
        const f32x16 z16 = {0.f};
        #pragma unroll
        for (int i = 0; i < 2; ++i)
            #pragma unroll
            for (int j = 0; j < 4; ++j) acc[i][j] = z16;

        bf16x8 ec[2], pc[4];
        ec[0] = *(const bf16x8*)(eb);
        ec[1] = *(const bf16x8*)(eb + 16 * 512);
        #pragma unroll
        for (int j = 0; j < 4; ++j) pc[j] = *(const bf16x8*)(zb + (j * 16) * 512);

        #pragma unroll 4
        for (int ks = 0; ks < 16; ++ks) {
            bf16x8 en[2], pn[4];
            if (ks < 15) {
                en[0] = *(const bf16x8*)(eb + (ks + 1) * 512);
                en[1] = *(const bf16x8*)(eb + (16 + ks + 1) * 512);
                #pragma unroll
                for (int j = 0; j < 4; ++j)
                    pn[j] = *(const bf16x8*)(zb + (j * 16 + ks + 1) * 512);
            }
            #pragma unroll
            for (int i = 0; i < 2; ++i)
                #pragma unroll
                for (int j = 0; j < 4; ++j)
                    acc[i][j] = __builtin_amdgcn_mfma_f32_32x32x16_bf16(
                        ec[i], pc[j], acc[i][j], 0, 0, 0);
            if (ks < 15) {
                ec[0] = en[0]; ec[1] = en[1];
                #pragma unroll
                for (int j = 0; j < 4; ++j) pc[j] = pn[j];
            }
        }

        // Epilogue: per code-frag, min over its 32 code-rows per point-lane.
        #pragma unroll
        for (int i = 0; i < 2; ++i) {
            const int cbase = cb + i * 32;
            float e2r[16];
            #pragma unroll
            for (int r = 0; r < 16; ++r)
                e2r[r] = e2[cbase + (r & 3) + 8 * (r >> 2) + 4 * l5];
            #pragma unroll
            for (int j = 0; j < 4; ++j) {
                float m = e2r[0] + acc[i][j][0];
                #pragma unroll
                for (int r = 1; r < 16; ++r) m = fminf(m, e2r[r] + acc[i][j][r]);
                m = fminf(m, __shfl_xor(m, 32));   // fold the two l5 halves
                if (l5 == 0)
                    tmin[(size_t)(n0 + j * 32 + c32) * 512 + (cbase >> 5)] = m;
            }
        }
    }
}

// ---------------------------------------------------------------------------
// Rescore: m1 = min over 512 group-mins; exact fp32 rescan of groups with
// gmin <= m1 + MARGIN; tie -> lowest j. Emits idxf + total_idx. Zeroes loss.
// ---------------------------------------------------------------------------
__global__ __launch_bounds__(256) void rescore(
    const float* __restrict__ tmin, const float* __restrict__ Zf32,
    const float* __restrict__ emb, const float* __restrict__ e2,
    int* __restrict__ idxf, float* __restrict__ out_idx,
    float* __restrict__ loss) {
    __shared__ float rbuf[4][256];
    const int tid = threadIdx.x, lane = tid & 63, w = tid >> 6;
    const int n = blockIdx.x * 4 + w;
    const int c32 = lane & 31, h = lane >> 5;
    if (blockIdx.x == 0 && tid == 0) loss[0] = 0.f;

    *(float4*)&rbuf[w][lane * 4] = *(const float4*)(Zf32 + (size_t)n * D + lane * 4);
    __syncthreads();

    float tv[8];
    #pragma unroll
    for (int gi = 0; gi < 8; ++gi) tv[gi] = tmin[(size_t)n * 512 + gi * 64 + lane];
    float m1 = tv[0];
    #pragma unroll
    for (int gi = 1; gi < 8; ++gi) m1 = fminf(m1, tv[gi]);
    #pragma unroll
    for (int st = 1; st < 64; st <<= 1) m1 = fminf(m1, __shfl_xor(m1, st));
    const float thresh = m1 + MARGIN;

    u64 best = ~0ull;
    const float* rr = &rbuf[w][h * 128];
    for (int gi = 0; gi < 8; ++gi) {
        u64 mask = __ballot(tv[gi] <= thresh);
        while (mask) {
            const int bit = (int)__builtin_ctzll(mask);
            mask &= mask - 1;
            const int g = gi * 64 + bit;
            const int c = g * 32 + c32;
            const float* er = emb + (size_t)c * D + h * 128;
            float s = 0.f;
            #pragma unroll
            for (int k = 0; k < 32; ++k) {
                const float4 ev = *(const float4*)(er + k * 4);
                s += rr[k * 4 + 0] * ev.x + rr[k * 4 + 1] * ev.y +
                     rr[k * 4 + 2] * ev.z + rr[k * 4 + 3] * ev.w;
            }
            s += __shfl_xor(s, 32);
            const float d = e2[c] - 2.0f * s;
            unsigned int u = __float_as_uint(d);
            u = (u & 0x80000000u) ? ~u : (u | 0x80000000u);
            const u64 key = ((u64)u << 32) | (unsigned int)c;
            if (key < best) best = key;
        }
    }
    #pragma unroll
    for (int st = 1; st < 32; st <<= 1) {
        const u64 o = __shfl_xor(best, st);
        if (o < best) best = o;
    }
    if (lane == 0) {
        const int bi = (int)(unsigned int)(best & 0xFFFFFFFFull);
        idxf[n] = bi;
        const int b = n >> 10, hw = n & 1023;
        const float fv = (float)bi;
        #pragma unroll
        for (int sc = 0; sc < 4; ++sc) out_idx[b * 4096 + sc * 1024 + hw] = fv;
    }
}

// ---------------------------------------------------------------------------
// Gather q = emb[idx]; z_hat_out = z + (4q - z); loss accumulation.
// 1024 blocks: (4 c-tiles of 64) x (8 b x 32 hw-tiles). 256 thr = 32 hw x 8 cg.
// ---------------------------------------------------------------------------
__global__ __launch_bounds__(256) void quant_loss(
    const float* __restrict__ z, const float* __restrict__ emb,
    const int* __restrict__ idxf, float* __restrict__ out,
    float* __restrict__ loss) {
    __shared__ int idx_l[32];
    __shared__ float wsum[4];
    const int blk = blockIdx.x;
    const int c0 = (blk >> 8) * 64;
    const int rem = blk & 255;
    const int b = rem >> 5, hw0 = (rem & 31) * 32;
    const int t = threadIdx.x, hw_l = t & 31, cg = t >> 5;
    if (t < 32) idx_l[t] = idxf[b * 1024 + hw0 + t];
    __syncthreads();
    const int j = idx_l[hw_l];
    const float* er = emb + (size_t)j * D + c0 + cg * 8;
    const float4 q0 = *(const float4*)er;
    const float4 q1 = *(const float4*)(er + 4);
    const float qv[8] = {q0.x, q0.y, q0.z, q0.w, q1.x, q1.y, q1.z, q1.w};
    float e = 0.f;
    #pragma unroll
    for (int cc = 0; cc < 8; ++cc) {
        const int c = c0 + cg * 8 + cc;
        const size_t zi = (size_t)b * 262144 + (size_t)c * 1024 + hw0 + hw_l;
        const float zv = z[zi];
        const float q = qv[cc];
        const float zh = ((q + q) + q) + q;   // mimic 4-step accumulation
        out[zi] = zv + (zh - zv);
        e += 30.0f * q * q - 20.0f * q * zv + 4.0f * zv * zv;
    }
    #pragma unroll
    for (int off = 32; off > 0; off >>= 1) e += __shfl_down(e, off);
    if ((t & 63) == 0) wsum[t >> 6] = e;
    __syncthreads();
    if (t == 0) {
        const float s = wsum[0] + wsum[1] + wsum[2] + wsum[3];
        atomicAdd(loss, s * (0.3125f / 2097152.0f));
    }
}

// ---------------------------------------------------------------------------
extern "C" void kernel_launch(void* const* d_in, const int* in_sizes, int n_in,
                              void* d_out, int out_size, void* d_ws, size_t ws_size,
                              hipStream_t stream) {
    const float* z = (const float*)d_in[0];     // [8,256,32,32]
    const float* emb = (const float*)d_in[1];   // [16384,256]
    float* out = (float*)d_out;                 // z_hat_out | loss | total_idx

    // Workspace (~36.1 MB)
    unsigned short* Zpk = (unsigned short*)d_ws;            // 8192*256 bf16
    unsigned short* Epk = Zpk + (size_t)NPTS * D;           // 16384*256 bf16
    float* Zf32 = (float*)(Epk + (size_t)N_E * D);          // 8192*256 f32
    float* e2 = Zf32 + (size_t)NPTS * D;                    // 16384 f32
    float* tmin = e2 + N_E;                                 // 8192*512 f32
    int* idxf = (int*)(tmin + (size_t)NPTS * 512);          // 8192 i32

    float* loss = out + ZOUT;
    float* out_idx = out + ZOUT + 1;

    prep<<<768, 256, 0, stream>>>(z, emb, Zpk, Zf32, Epk, e2);
    mfma_gemm<<<dim3(NPTS / 128, N_E / (256 * STRIPS)), 256, 0, stream>>>(
        Epk, Zpk, e2, tmin);
    rescore<<<NPTS / 4, 256, 0, stream>>>(tmin, Zf32, emb, e2, idxf, out_idx, loss);
    quant_loss<<<1024, 256, 0, stream>>>(z, emb, idxf, out, loss);
}